// Round 1
// baseline (78.798 us; speedup 1.0000x reference)
//
#include <hip/hip_runtime.h>
#include <math.h>

#define T_LEN   2400
#define NTAPS   16
#define FRAME   160
#define NFRAMES 15
#define OPT     8                 // outputs per thread; 160 % 8 == 0 -> one LPC frame per thread
#define GPR     (T_LEN / OPT)     // 300 output groups per row
#define WLEN    (NTAPS + OPT)     // 24-float input window per thread
#define NLD     (WLEN / 4)        // 6 float4 window loads

#define SCALE_C    (255.0f / 32768.0f)
#define SCALE_1_C  (32768.0f / 255.0f)

// u2l: s * (32768/255) * (2^(|u|/16) - 1); note u2l(128.0) == 0 exactly (pad trick)
__device__ __forceinline__ float u2l_f(float uv) {
    float u = uv - 128.0f;
    float a = fabsf(u);
    float m = SCALE_1_C * (exp2f(a * 0.0625f) - 1.0f);
    return copysignf(m, u);
}

// l2u: clip(128 + s*16*log2(1 + SCALE*|x|), 0, 255)
__device__ __forceinline__ float l2u_f(float x) {
    float a = fabsf(x);
    float u = 16.0f * log2f(fmaf(SCALE_C, a, 1.0f));
    u = copysignf(u, x);
    float r = 128.0f + u;
    return fminf(fmaxf(r, 0.0f), 255.0f);
}

// Pure streaming kernel: no LDS, no __syncthreads. Each thread produces 8
// consecutive outputs of one row. Window reuse (3x read amplification) is
// served by L1/L2 -- adjacent threads read adjacent, overlapping 16B lines.
__global__ __launch_bounds__(256) void diff_pred_kernel(
        const float* __restrict__ sig,
        const float* __restrict__ lpc,
        float* __restrict__ out,
        int total) {
    const int g = blockIdx.x * 256 + threadIdx.x;
    if (g >= total) return;

    const int row = g / GPR;          // batch row (compiler emits magic-mul for /300)
    const int rt  = g - row * GPR;    // group index within row, 0..299
    const int t0  = rt * OPT;         // first output index, multiple of 8

    const float* sig_b = sig + (size_t)row * T_LEN;

    // ---- issue all window loads first (ILP), clamped in-bounds ----
    // Window covers xt[t0-16 .. t0+7]. Each float4 is entirely in-range or
    // entirely in the zero-pad (offsets are multiples of 4). Pad float4s get
    // raw value 128.0, which u2l decodes to exactly 0 -- branchless, in-bounds.
    float4 rv[NLD];
    #pragma unroll
    for (int r = 0; r < NLD; ++r) {
        const int off  = t0 - NTAPS + 4 * r;
        const int soff = off < 0 ? 0 : off;          // keep address in-bounds
        float4 v = *(const float4*)(sig_b + soff);   // 16B-aligned always
        if (off < 0) v = make_float4(128.0f, 128.0f, 128.0f, 128.0f);
        rv[r] = v;
    }

    // ---- coefficient loads: one frame per thread (t0%160 <= 152) ----
    const int f = rt / (FRAME / OPT);                // rt / 20 -> frame 0..14
    const float* lpc_b = lpc + (size_t)row * (NFRAMES * NTAPS) + f * NTAPS;
    const float4 c0 = *(const float4*)(lpc_b + 0);   // 64B-aligned, broadcast-friendly
    const float4 c1 = *(const float4*)(lpc_b + 4);
    const float4 c2 = *(const float4*)(lpc_b + 8);
    const float4 c3 = *(const float4*)(lpc_b + 12);
    const float c[NTAPS] = {c0.x, c0.y, c0.z, c0.w, c1.x, c1.y, c1.z, c1.w,
                            c2.x, c2.y, c2.z, c2.w, c3.x, c3.y, c3.z, c3.w};

    // ---- decode window (each input decoded once per owning thread) ----
    float w[WLEN];
    #pragma unroll
    for (int r = 0; r < NLD; ++r) {
        w[4*r+0] = u2l_f(rv[r].x);
        w[4*r+1] = u2l_f(rv[r].y);
        w[4*r+2] = u2l_f(rv[r].z);
        w[4*r+3] = u2l_f(rv[r].w);
    }

    // ---- 16-tap FIR for 8 outputs: out[t0+k] = -sum_j c[j]*xt[t0+k-j] ----
    float acc[OPT] = {0.0f, 0.0f, 0.0f, 0.0f, 0.0f, 0.0f, 0.0f, 0.0f};
    #pragma unroll
    for (int j = 0; j < NTAPS; ++j) {
        #pragma unroll
        for (int k = 0; k < OPT; ++k) {
            acc[k] = fmaf(c[j], w[NTAPS + k - j], acc[k]);
        }
    }

    // ---- encode + store: 2 x float4, 64B-aligned per thread ----
    float4 o0, o1;
    o0.x = l2u_f(-acc[0]); o0.y = l2u_f(-acc[1]);
    o0.z = l2u_f(-acc[2]); o0.w = l2u_f(-acc[3]);
    o1.x = l2u_f(-acc[4]); o1.y = l2u_f(-acc[5]);
    o1.z = l2u_f(-acc[6]); o1.w = l2u_f(-acc[7]);

    float* out_b = out + (size_t)row * T_LEN + t0;
    *(float4*)(out_b + 0) = o0;
    *(float4*)(out_b + 4) = o1;
}

extern "C" void kernel_launch(void* const* d_in, const int* in_sizes, int n_in,
                              void* d_out, int out_size, void* d_ws, size_t ws_size,
                              hipStream_t stream) {
    const float* sig = (const float*)d_in[0];   // (2048, 2400, 1) f32
    const float* lpc = (const float*)d_in[1];   // (2048, 15, 16) f32
    float* out = (float*)d_out;                  // (2048, 2400, 1) f32

    const int batch = in_sizes[0] / T_LEN;       // 2048
    const int total = batch * GPR;               // 614400 threads
    const int nblk  = (total + 255) / 256;       // 2400 blocks
    diff_pred_kernel<<<nblk, 256, 0, stream>>>(sig, lpc, out, total);
}